// Round 2
// baseline (393.455 us; speedup 1.0000x reference)
//
#include <hip/hip_runtime.h>
#include <hip/hip_bf16.h>

// Sizes (fixed by the reference)
#define BATCH 8192
#define DIM   128
#define NPAT  64
#define VOCAB 32000

typedef __attribute__((ext_vector_type(8))) short short8;   // 8 bf16 = 4 VGPRs
typedef __attribute__((ext_vector_type(4))) float f32x4;    // MFMA accum

// ---------------------------------------------------------------------------
// Phase A: per-row attention/softmax/rec/self-gate, all f32, output gated bf16.
// One wave per batch row, 4 rows (4 waves) per block.
// ---------------------------------------------------------------------------
__global__ __launch_bounds__(256) void phaseA_kernel(
    const float* __restrict__ x,            // [B, D]
    const float* __restrict__ attn_w,       // [D, P]
    const float* __restrict__ attn_b,       // [P]
    const float* __restrict__ pattern_dict, // [P, D]
    const float* __restrict__ self_w,       // [D, D]
    const float* __restrict__ self_b,       // [D]
    __hip_bfloat16* __restrict__ gated)     // [B, D] bf16 out
{
    __shared__ float xs[4][DIM];
    __shared__ float wls[4][NPAT];
    __shared__ float recs[4][DIM];

    const int lane = threadIdx.x & 63;
    const int wid  = threadIdx.x >> 6;
    const int row  = blockIdx.x * 4 + wid;

    // stage x row in LDS (broadcast source)
    xs[wid][lane]      = x[row * DIM + lane];
    xs[wid][lane + 64] = x[row * DIM + 64 + lane];
    __syncthreads();

    // logits[p] for p = lane (P == 64 == wave width)
    float acc = attn_b[lane];
#pragma unroll 8
    for (int d = 0; d < DIM; ++d)
        acc += xs[wid][d] * attn_w[d * NPAT + lane];

    // softmax over the 64 lanes
    float m = acc;
#pragma unroll
    for (int o = 32; o; o >>= 1) m = fmaxf(m, __shfl_xor(m, o));
    float e = expf(acc - m);
    float s = e;
#pragma unroll
    for (int o = 32; o; o >>= 1) s += __shfl_xor(s, o);
    float w = e / s;
    wls[wid][lane] = w;
    __syncthreads();

    // rec[d] = sum_p w[p] * pattern_dict[p][d]; lane owns d = lane, lane+64
    float r0 = 0.f, r1 = 0.f;
#pragma unroll 8
    for (int p = 0; p < NPAT; ++p) {
        float wp = wls[wid][p];
        r0 += wp * pattern_dict[p * DIM + lane];
        r1 += wp * pattern_dict[p * DIM + 64 + lane];
    }
    recs[wid][lane]      = r0;
    recs[wid][lane + 64] = r1;
    __syncthreads();

    // self_pred = rec @ self_w + self_b
    float s0 = self_b[lane], s1 = self_b[lane + 64];
#pragma unroll 8
    for (int k = 0; k < DIM; ++k) {
        float rk = recs[wid][k];
        s0 += rk * self_w[k * DIM + lane];
        s1 += rk * self_w[k * DIM + 64 + lane];
    }

    // paradox gate
    float p0 = s0 - r0, p1 = s1 - r1;
    float ss = p0 * p0 + p1 * p1;
#pragma unroll
    for (int o = 32; o; o >>= 1) ss += __shfl_xor(ss, o);
    float mag = sqrtf(ss);
    float g = 1.f / (1.f + expf(-mag));

    gated[row * DIM + lane]      = __float2bfloat16(r0 * g);
    gated[row * DIM + 64 + lane] = __float2bfloat16(r1 * g);
}

// ---------------------------------------------------------------------------
// Transpose + convert: out_w [D=128, V=32000] f32  ->  out_w_t [V, D] bf16.
// Block handles a 64-column (n) strip across all 128 k. LDS tile transpose.
// ---------------------------------------------------------------------------
__global__ __launch_bounds__(256) void transpose_w_kernel(
    const float* __restrict__ out_w,        // [D, V]
    __hip_bfloat16* __restrict__ owt)       // [V, D]
{
    __shared__ __hip_bfloat16 tile[64][136]; // 136: keep 16B alignment, break bank stride

    const int t  = threadIdx.x;
    const int n0 = blockIdx.x * 64;
    const int c  = t & 63;   // n within strip
    const int k0 = t >> 6;   // 0..3

    // coalesced f32 reads: for each k, 64 lanes read consecutive n
    for (int kk = 0; kk < DIM; kk += 4) {
        int k = kk + k0;
        tile[c][k] = __float2bfloat16(out_w[(size_t)k * VOCAB + n0 + c]);
    }
    __syncthreads();

    // coalesced bf16 writes: thread t writes 32 bf16 (64 B) of one output row
    const int row = t >> 2, seg = t & 3;
    const uint4* src = reinterpret_cast<const uint4*>(&tile[row][seg * 32]);
    uint4* dst = reinterpret_cast<uint4*>(&owt[(size_t)(n0 + row) * DIM + seg * 32]);
    dst[0] = src[0];
    dst[1] = src[1];
    dst[2] = src[2];
    dst[3] = src[3];
}

// ---------------------------------------------------------------------------
// GEMM: out[B,V] = gated[B,D](bf16) @ out_w_t[V,D]^T (bf16) + out_b, f32 out.
// K = 128 total -> no LDS, no barriers: each wave loads its MFMA fragments
// straight from L2 and does 64 x mfma_f32_16x16x32_bf16.
// Block = 256 thr = 2x2 waves, block tile 128x128, wave tile 64x64.
// Grid: blockIdx.x = m-block (fast, 64), blockIdx.y = n-panel (slow, 250)
// so each B-panel is HBM-fetched once and reused by 64 consecutive blocks.
// ---------------------------------------------------------------------------
__global__ __launch_bounds__(256) void gemm_out_kernel(
    const __hip_bfloat16* __restrict__ A,   // gated [B, D]
    const __hip_bfloat16* __restrict__ Bt,  // out_w_t [V, D]
    const float* __restrict__ bias,         // [V]
    float* __restrict__ out)                // [B, V]
{
    const int tid  = threadIdx.x;
    const int lane = tid & 63;
    const int wid  = tid >> 6;
    const int wm   = wid >> 1;        // 0..1
    const int wn   = wid & 1;         // 0..1
    const int m0   = blockIdx.x * 128 + wm * 64;
    const int n0   = blockIdx.y * 128 + wn * 64;
    const int r16  = lane & 15;
    const int kq   = lane >> 4;       // 0..3 (k-quarter: 8 contiguous bf16)

    f32x4 acc[4][4] = {}; // [mi][ni], each 4 f32 (rows (lane>>4)*4+r, col r16)

#pragma unroll
    for (int ks = 0; ks < 4; ++ks) {  // K-step of 32
        short8 a[4], b[4];
#pragma unroll
        for (int i = 0; i < 4; ++i) {
            a[i] = *reinterpret_cast<const short8*>(
                A + (size_t)(m0 + i * 16 + r16) * DIM + ks * 32 + kq * 8);
            b[i] = *reinterpret_cast<const short8*>(
                Bt + (size_t)(n0 + i * 16 + r16) * DIM + ks * 32 + kq * 8);
        }
#pragma unroll
        for (int mi = 0; mi < 4; ++mi)
#pragma unroll
            for (int ni = 0; ni < 4; ++ni)
                acc[mi][ni] = __builtin_amdgcn_mfma_f32_16x16x32_bf16(
                    a[mi], b[ni], acc[mi][ni], 0, 0, 0);
    }

    // epilogue: bias + store. D layout: col = lane&15, row = (lane>>4)*4 + r
    float bv[4];
#pragma unroll
    for (int ni = 0; ni < 4; ++ni) bv[ni] = bias[n0 + ni * 16 + r16];

    const int rowbase = (lane >> 4) * 4;
#pragma unroll
    for (int mi = 0; mi < 4; ++mi) {
#pragma unroll
        for (int ni = 0; ni < 4; ++ni) {
            const int col = n0 + ni * 16 + r16;
#pragma unroll
            for (int r = 0; r < 4; ++r) {
                const int row = m0 + mi * 16 + rowbase + r;
                out[(size_t)row * VOCAB + col] = acc[mi][ni][r] + bv[ni];
            }
        }
    }
}

// ---------------------------------------------------------------------------
extern "C" void kernel_launch(void* const* d_in, const int* in_sizes, int n_in,
                              void* d_out, int out_size, void* d_ws, size_t ws_size,
                              hipStream_t stream) {
    const float* x            = (const float*)d_in[0];
    const float* pattern_dict = (const float*)d_in[1];
    const float* attn_w       = (const float*)d_in[2];
    const float* attn_b       = (const float*)d_in[3];
    const float* self_w       = (const float*)d_in[4];
    const float* self_b       = (const float*)d_in[5];
    const float* out_w        = (const float*)d_in[6];
    const float* out_b        = (const float*)d_in[7];
    float* out = (float*)d_out;

    // workspace: gated bf16 [B,D] (2 MB) | out_w_t bf16 [V,D] (8.2 MB)
    __hip_bfloat16* gated = (__hip_bfloat16*)d_ws;
    __hip_bfloat16* owt   = (__hip_bfloat16*)((char*)d_ws + (size_t)BATCH * DIM * 2);

    phaseA_kernel<<<BATCH / 4, 256, 0, stream>>>(
        x, attn_w, attn_b, pattern_dict, self_w, self_b, gated);
    transpose_w_kernel<<<VOCAB / 64, 256, 0, stream>>>(out_w, owt);
    gemm_out_kernel<<<dim3(BATCH / 128, VOCAB / 128), 256, 0, stream>>>(
        gated, owt, out_b, out);
}

// Round 3
// 381.117 us; speedup vs baseline: 1.0324x; 1.0324x over previous
//
#include <hip/hip_runtime.h>
#include <hip/hip_bf16.h>

// Sizes (fixed by the reference)
#define BATCH 8192
#define DIM   128
#define NPAT  64
#define VOCAB 32000

typedef __attribute__((ext_vector_type(8))) short short8;   // 8 bf16 = 4 VGPRs
typedef __attribute__((ext_vector_type(4))) float f32x4;    // MFMA accum

// ---------------------------------------------------------------------------
// Phase A: per-row attention/softmax/rec/self-gate, all f32, output gated bf16.
// One wave per batch row, 4 rows (4 waves) per block.
// ---------------------------------------------------------------------------
__global__ __launch_bounds__(256) void phaseA_kernel(
    const float* __restrict__ x,            // [B, D]
    const float* __restrict__ attn_w,       // [D, P]
    const float* __restrict__ attn_b,       // [P]
    const float* __restrict__ pattern_dict, // [P, D]
    const float* __restrict__ self_w,       // [D, D]
    const float* __restrict__ self_b,       // [D]
    __hip_bfloat16* __restrict__ gated)     // [B, D] bf16 out
{
    __shared__ float xs[4][DIM];
    __shared__ float wls[4][NPAT];
    __shared__ float recs[4][DIM];

    const int lane = threadIdx.x & 63;
    const int wid  = threadIdx.x >> 6;
    const int row  = blockIdx.x * 4 + wid;

    // stage x row in LDS (broadcast source)
    xs[wid][lane]      = x[row * DIM + lane];
    xs[wid][lane + 64] = x[row * DIM + 64 + lane];
    __syncthreads();

    // logits[p] for p = lane (P == 64 == wave width)
    float acc = attn_b[lane];
#pragma unroll 8
    for (int d = 0; d < DIM; ++d)
        acc += xs[wid][d] * attn_w[d * NPAT + lane];

    // softmax over the 64 lanes
    float m = acc;
#pragma unroll
    for (int o = 32; o; o >>= 1) m = fmaxf(m, __shfl_xor(m, o));
    float e = expf(acc - m);
    float s = e;
#pragma unroll
    for (int o = 32; o; o >>= 1) s += __shfl_xor(s, o);
    float w = e / s;
    wls[wid][lane] = w;
    __syncthreads();

    // rec[d] = sum_p w[p] * pattern_dict[p][d]; lane owns d = lane, lane+64
    float r0 = 0.f, r1 = 0.f;
#pragma unroll 8
    for (int p = 0; p < NPAT; ++p) {
        float wp = wls[wid][p];
        r0 += wp * pattern_dict[p * DIM + lane];
        r1 += wp * pattern_dict[p * DIM + 64 + lane];
    }
    recs[wid][lane]      = r0;
    recs[wid][lane + 64] = r1;
    __syncthreads();

    // self_pred = rec @ self_w + self_b
    float s0 = self_b[lane], s1 = self_b[lane + 64];
#pragma unroll 8
    for (int k = 0; k < DIM; ++k) {
        float rk = recs[wid][k];
        s0 += rk * self_w[k * DIM + lane];
        s1 += rk * self_w[k * DIM + 64 + lane];
    }

    // paradox gate
    float p0 = s0 - r0, p1 = s1 - r1;
    float ss = p0 * p0 + p1 * p1;
#pragma unroll
    for (int o = 32; o; o >>= 1) ss += __shfl_xor(ss, o);
    float mag = sqrtf(ss);
    float g = 1.f / (1.f + expf(-mag));

    gated[row * DIM + lane]      = __float2bfloat16(r0 * g);
    gated[row * DIM + 64 + lane] = __float2bfloat16(r1 * g);
}

// ---------------------------------------------------------------------------
// Transpose + convert: out_w [D=128, V=32000] f32  ->  out_w_t [V, D] bf16.
// Block handles a 64-column (n) strip across all 128 k. LDS tile transpose.
// ---------------------------------------------------------------------------
__global__ __launch_bounds__(256) void transpose_w_kernel(
    const float* __restrict__ out_w,        // [D, V]
    __hip_bfloat16* __restrict__ owt)       // [V, D]
{
    __shared__ __hip_bfloat16 tile[64][136]; // 136: keep 16B alignment, break bank stride

    const int t  = threadIdx.x;
    const int n0 = blockIdx.x * 64;
    const int c  = t & 63;   // n within strip
    const int k0 = t >> 6;   // 0..3

    // coalesced f32 reads: for each k, 64 lanes read consecutive n
    for (int kk = 0; kk < DIM; kk += 4) {
        int k = kk + k0;
        tile[c][k] = __float2bfloat16(out_w[(size_t)k * VOCAB + n0 + c]);
    }
    __syncthreads();

    // coalesced bf16 writes: thread t writes 32 bf16 (64 B) of one output row
    const int row = t >> 2, seg = t & 3;
    const uint4* src = reinterpret_cast<const uint4*>(&tile[row][seg * 32]);
    uint4* dst = reinterpret_cast<uint4*>(&owt[(size_t)(n0 + row) * DIM + seg * 32]);
    dst[0] = src[0];
    dst[1] = src[1];
    dst[2] = src[2];
    dst[3] = src[3];
}

// ---------------------------------------------------------------------------
// GEMM: out[B,V] = gated[B,D](bf16) @ out_w_t[V,D]^T (bf16) + out_b, f32 out.
// K = 128 total -> no LDS, no barriers: fragments straight from L2,
// 64 x mfma_f32_16x16x32_bf16 per wave.
//
// OPERANDS SWAPPED vs naive: acc = mfma(b[ni], a[mi], acc) computes
// D[n][m] with layout col(=m) = lane&15, row(=n) = (lane>>4)*4 + reg.
// The 4 regs of each accumulator span 4 CONSECUTIVE n at fixed m, so the
// epilogue stores one aligned float4 per lane per (mi,ni) -> 16 stores/wave
// of 1 KB each instead of 64 stores of 256 B. Stores are non-temporal:
// the 1.05 GB output is write-once, keep L2/L3 for A/B panels.
//
// __launch_bounds__(256,4): cap VGPR at 128 (64 acc + 32 per-ks frags + addr)
// so 4 waves/SIMD hide the L2 fragment-load latency.
// ---------------------------------------------------------------------------
__global__ __launch_bounds__(256, 4) void gemm_out_kernel(
    const __hip_bfloat16* __restrict__ A,   // gated [B, D]
    const __hip_bfloat16* __restrict__ Bt,  // out_w_t [V, D]
    const float* __restrict__ bias,         // [V]
    float* __restrict__ out)                // [B, V]
{
    const int tid  = threadIdx.x;
    const int lane = tid & 63;
    const int wid  = tid >> 6;
    const int wm   = wid >> 1;        // 0..1
    const int wn   = wid & 1;         // 0..1
    const int m0   = blockIdx.x * 128 + wm * 64;
    const int n0   = blockIdx.y * 128 + wn * 64;
    const int r16  = lane & 15;
    const int kq   = lane >> 4;       // 0..3 (k-quarter: 8 contiguous bf16)

    f32x4 acc[4][4] = {}; // [mi][ni]; reg r = n offset (lane>>4)*4 + r, m = lane&15

    for (int ks = 0; ks < 4; ++ks) {  // K-step of 32
        short8 a[4], b[4];
#pragma unroll
        for (int i = 0; i < 4; ++i) {
            a[i] = *reinterpret_cast<const short8*>(
                A + (size_t)(m0 + i * 16 + r16) * DIM + ks * 32 + kq * 8);
            b[i] = *reinterpret_cast<const short8*>(
                Bt + (size_t)(n0 + i * 16 + r16) * DIM + ks * 32 + kq * 8);
        }
#pragma unroll
        for (int mi = 0; mi < 4; ++mi)
#pragma unroll
            for (int ni = 0; ni < 4; ++ni)
                acc[mi][ni] = __builtin_amdgcn_mfma_f32_16x16x32_bf16(
                    b[ni], a[mi], acc[mi][ni], 0, 0, 0);
    }

    // epilogue: D[n][m] layout -> lane owns m = m0+mi*16+(lane&15),
    // n = n0+ni*16+(lane>>4)*4 + r. One float4 nt-store per (mi,ni).
    const int g = lane >> 4;
    f32x4 bb[4];
#pragma unroll
    for (int ni = 0; ni < 4; ++ni)
        bb[ni] = *reinterpret_cast<const f32x4*>(bias + n0 + ni * 16 + g * 4);

#pragma unroll
    for (int mi = 0; mi < 4; ++mi) {
        const size_t rowoff = (size_t)(m0 + mi * 16 + r16) * VOCAB;
#pragma unroll
        for (int ni = 0; ni < 4; ++ni) {
            f32x4 v = acc[mi][ni] + bb[ni];
            f32x4* dst = reinterpret_cast<f32x4*>(
                out + rowoff + n0 + ni * 16 + g * 4);
            __builtin_nontemporal_store(v, dst);
        }
    }
}

// ---------------------------------------------------------------------------
extern "C" void kernel_launch(void* const* d_in, const int* in_sizes, int n_in,
                              void* d_out, int out_size, void* d_ws, size_t ws_size,
                              hipStream_t stream) {
    const float* x            = (const float*)d_in[0];
    const float* pattern_dict = (const float*)d_in[1];
    const float* attn_w       = (const float*)d_in[2];
    const float* attn_b       = (const float*)d_in[3];
    const float* self_w       = (const float*)d_in[4];
    const float* self_b       = (const float*)d_in[5];
    const float* out_w        = (const float*)d_in[6];
    const float* out_b        = (const float*)d_in[7];
    float* out = (float*)d_out;

    // workspace: gated bf16 [B,D] (2 MB) | out_w_t bf16 [V,D] (8.2 MB)
    __hip_bfloat16* gated = (__hip_bfloat16*)d_ws;
    __hip_bfloat16* owt   = (__hip_bfloat16*)((char*)d_ws + (size_t)BATCH * DIM * 2);

    phaseA_kernel<<<BATCH / 4, 256, 0, stream>>>(
        x, attn_w, attn_b, pattern_dict, self_w, self_b, gated);
    transpose_w_kernel<<<VOCAB / 64, 256, 0, stream>>>(out_w, owt);
    gemm_out_kernel<<<dim3(BATCH / 128, VOCAB / 128), 256, 0, stream>>>(
        gated, owt, out_b, out);
}